// Round 1
// 673.621 us; speedup vs baseline: 1.1024x; 1.1024x over previous
//
#include <hip/hip_runtime.h>
#include <cstdint>
#include <cstddef>

#define D_MODEL 1024
#define SEQ 8192

typedef __bf16  bf16x8 __attribute__((ext_vector_type(8)));
typedef short   short8 __attribute__((ext_vector_type(8)));
typedef float   f32x4  __attribute__((ext_vector_type(4)));
typedef unsigned short ushort_t;

__device__ __forceinline__ ushort_t f2bf(float f) {
  uint32_t u = __builtin_bit_cast(uint32_t, f);
  u += 0x7FFFu + ((u >> 16) & 1u);          // round-to-nearest-even
  return (ushort_t)(u >> 16);
}
// async global->LDS, 16B per lane. LDS dest is wave-uniform base + lane*16.
__device__ __forceinline__ void gll16(const void* g, void* l) {
  __builtin_amdgcn_global_load_lds(
      (const __attribute__((address_space(1))) void*)g,
      (__attribute__((address_space(3))) void*)l, 16, 0, 0);
}
// stage one 128x64 bf16 half-tile (16 KB): 2 gll16 per thread.
__device__ __forceinline__ void stage_half(const ushort_t* g, char* l0) {
  gll16(g, l0);                       // rows  0..63 of half
  gll16(g + 65536, l0 + 8192);        // rows 64..127 of half (+64*1024 elems)
}

// ---------------- fp32 -> bf16 conversion of x ----------------
__global__ void k_convert_x(const float* __restrict__ x, ushort_t* __restrict__ xb, int n) {
  int i = (blockIdx.x * 256 + threadIdx.x) * 8;
  if (i >= n) return;
  float4 v0 = *(const float4*)(x + i);
  float4 v1 = *(const float4*)(x + i + 4);
  ushort_t o[8] = { f2bf(v0.x), f2bf(v0.y), f2bf(v0.z), f2bf(v0.w),
                    f2bf(v1.x), f2bf(v1.y), f2bf(v1.z), f2bf(v1.w) };
  *(short8*)(xb + i) = *(const short8*)o;
}

// ---------------- W (k,n) fp32 -> Wt (n,k) bf16; z<3 -> fused qkv buffer ----------------
__global__ void k_transpose_w(const float* W0, const float* W1, const float* W2, const float* W3,
                              ushort_t* Tqkv, ushort_t* To) {
  const float* src; ushort_t* dst;
  switch (blockIdx.z) {
    case 0: src = W0; dst = Tqkv; break;
    case 1: src = W1; dst = Tqkv + (size_t)1024 * 1024; break;
    case 2: src = W2; dst = Tqkv + (size_t)2048 * 1024; break;
    default: src = W3; dst = To; break;
  }
  __shared__ float tile[64][65];
  int tx = threadIdx.x;
  int c = tx & 63, r0 = tx >> 6;
  int bx = blockIdx.x * 64, by = blockIdx.y * 64;
  #pragma unroll
  for (int i = 0; i < 16; i++) {
    int r = i * 4 + r0;
    tile[r][c] = src[(size_t)(by + r) * D_MODEL + bx + c];
  }
  __syncthreads();
  #pragma unroll
  for (int i = 0; i < 16; i++) {
    int r = i * 4 + r0;
    dst[(size_t)(bx + r) * D_MODEL + by + c] = f2bf(tile[c][r]);
  }
}

// ---------------- 256x256-tile 8-phase bf16 GEMM: C = A(M,K) * Bt(N,K)^T + bias ----------------
// m201-style schedule: BK=64, 8 waves (2Mx4N), LDS 128KB double-buffered,
// T2 chunk-XOR swizzle (pre-swizzled global src + swizzled ds_read),
// T3/T4 counted vmcnt(6) at K-tile boundaries only, T5 setprio around MFMA,
// T1 bijective XCD swizzle on the 1D grid (nwg % 8 == 0).
// MODE 0: fused QKV (N=3072): region 0/1 -> elu+1 -> o0/o1; region 2 -> o2. bf16 out.
// MODE 2: fp32 out (+bias), single output.
template<int MODE, int NY>
__global__ __launch_bounds__(512, 2) void k_gemm(const ushort_t* __restrict__ A,
                                                 const ushort_t* __restrict__ Bt,
                                                 const float* __restrict__ b0,
                                                 const float* __restrict__ b1,
                                                 const float* __restrict__ b2,
                                                 ushort_t* __restrict__ o0,
                                                 ushort_t* __restrict__ o1,
                                                 ushort_t* __restrict__ o2,
                                                 float* __restrict__ outf) {
  __shared__ __align__(16) char smem[131072];   // 2 x (A 32KB + B 32KB) dbuf; epilogue reuses

  const int nwg = gridDim.x;
  const int bid0 = blockIdx.x;
  const int bid = (bid0 & 7) * (nwg >> 3) + (bid0 >> 3);   // XCD-aware, bijective (nwg%8==0)
  const int xb = bid / NY, yb = bid % NY;                  // N-fastest: A-panel L2 reuse
  const int m0 = xb * 256, n0 = yb * 256;

  const int tid = threadIdx.x;
  const int ln = tid & 63;
  const int w  = tid >> 6;
  const int wb = __builtin_amdgcn_readfirstlane(w);
  const int wm = wb >> 2, wn = wb & 3;          // 2x4 wave grid; per-wave C = 128x64

  // --- staging: thread's (row,chunk) slot; global chunk pre-swizzled (c ^= row&7) ---
  const int srow = wb * 8 + (ln >> 3);                       // row in half-tile (load0)
  const int schk = ((ln & 7) ^ ((ln >> 3) & 7)) * 8;         // swizzled source chunk (elems)
  const ushort_t* gA = A  + (size_t)(m0 + srow) * D_MODEL + schk;
  const ushort_t* gB = Bt + (size_t)(n0 + srow) * D_MODEL + schk;

#define STAGE_A(BUF, H, T) stage_half(gA + (size_t)(T) * 64 + (size_t)(H) * 131072, (BUF) + (H) * 16384 + wb * 1024)
#define STAGE_B(BUF, H, T) stage_half(gB + (size_t)(T) * 64 + (size_t)(H) * 131072, (BUF) + 32768 + (H) * 16384 + wb * 1024)

  char* cur = smem;
  char* nxt = smem + 65536;
  // prologue: tile0 all 4 halves; tile1 {B0,B1,A0} (A1 staged at block0 ph0)
  STAGE_B(cur, 0, 0); STAGE_B(cur, 1, 0); STAGE_A(cur, 0, 0); STAGE_A(cur, 1, 0);
  STAGE_B(nxt, 0, 1); STAGE_B(nxt, 1, 1); STAGE_A(nxt, 0, 1);
  asm volatile("s_waitcnt vmcnt(6)" ::: "memory");           // tile0 landed; 3 halves in flight
  __builtin_amdgcn_s_barrier();

  f32x4 acc[8][4];
  #pragma unroll
  for (int i = 0; i < 8; i++)
    #pragma unroll
    for (int j = 0; j < 4; j++) acc[i][j] = (f32x4){0.f, 0.f, 0.f, 0.f};
  bf16x8 fa[4][2], fb0[2][2], fb1[2][2];

  const int ar  = ln & 15;
  const int cw0 = (((ln >> 4)    ) ^ (ln & 7)) << 4;         // swizzled 16B chunk offs, ksub0
  const int cw1 = (((ln >> 4) + 4) ^ (ln & 7)) << 4;         // ksub1
  const int arow = wm * 128 + ar;
  const int brow = wn * 64 + ar;

#define LDA(MH) { _Pragma("unroll") for (int mi = 0; mi < 4; ++mi) { \
    const char* p_ = cur + ((arow + (MH) * 64 + mi * 16) << 7); \
    fa[mi][0] = *(const bf16x8*)(p_ + cw0); fa[mi][1] = *(const bf16x8*)(p_ + cw1); } }
#define LDB(FB, NH) { _Pragma("unroll") for (int nj = 0; nj < 2; ++nj) { \
    const char* p_ = cur + 32768 + ((brow + (NH) * 32 + nj * 16) << 7); \
    FB[nj][0] = *(const bf16x8*)(p_ + cw0); FB[nj][1] = *(const bf16x8*)(p_ + cw1); } }
#define QUAD(MH, NH, FB) { _Pragma("unroll") for (int mi = 0; mi < 4; ++mi) \
    _Pragma("unroll") for (int nj = 0; nj < 2; ++nj) { \
      acc[(MH)*4+mi][(NH)*2+nj] = __builtin_amdgcn_mfma_f32_16x16x32_bf16(fa[mi][0], FB[nj][0], acc[(MH)*4+mi][(NH)*2+nj], 0, 0, 0); \
      acc[(MH)*4+mi][(NH)*2+nj] = __builtin_amdgcn_mfma_f32_16x16x32_bf16(fa[mi][1], FB[nj][1], acc[(MH)*4+mi][(NH)*2+nj], 0, 0, 0); } }
#define PHASE_SYNC { __builtin_amdgcn_s_barrier(); \
                     asm volatile("s_waitcnt lgkmcnt(0)" ::: "memory"); \
                     __builtin_amdgcn_sched_barrier(0); }

  #pragma unroll 2
  for (int kt = 0; kt < 16; ++kt) {
    const bool st1 = (kt + 1 < 16);
    const bool st2 = (kt + 2 < 16);
    // ph0: quadrant (0,0); stage A1(kt+1) -> nxt (other buffer: never conflicts)
    LDA(0); LDB(fb0, 0);
    if (st1) STAGE_A(nxt, 1, kt + 1);
    PHASE_SYNC;
    __builtin_amdgcn_s_setprio(1); QUAD(0, 0, fb0); __builtin_amdgcn_s_setprio(0);
    __builtin_amdgcn_s_barrier();
    // ph1: quadrant (0,1)  (all B reads for this tile complete after this phase)
    LDB(fb1, 1);
    PHASE_SYNC;
    __builtin_amdgcn_s_setprio(1); QUAD(0, 1, fb1); __builtin_amdgcn_s_setprio(0);
    __builtin_amdgcn_s_barrier();
    // ph2: quadrant (1,1); stage B0(kt+2) -> cur (B0 readers finished ph1)
    LDA(1);
    if (st2) STAGE_B(cur, 0, kt + 2);
    PHASE_SYNC;
    __builtin_amdgcn_s_setprio(1); QUAD(1, 1, fb1); __builtin_amdgcn_s_setprio(0);
    __builtin_amdgcn_s_barrier();
    // ph3: quadrant (1,0); stage B1,A0(kt+2) -> cur (readers finished ph1/ph2)
    if (st2) { STAGE_B(cur, 1, kt + 2); STAGE_A(cur, 0, kt + 2); }
    __builtin_amdgcn_s_barrier();
    __builtin_amdgcn_s_setprio(1); QUAD(1, 0, fb0); __builtin_amdgcn_s_setprio(0);
    if (kt < 14)       asm volatile("s_waitcnt vmcnt(6)" ::: "memory");  // kt+1 landed; 3 halves of kt+2 in flight
    else if (kt == 14) asm volatile("s_waitcnt vmcnt(0)" ::: "memory");  // drain for last tile
    __builtin_amdgcn_s_barrier();
    char* t_ = cur; cur = nxt; nxt = t_;
  }
#undef STAGE_A
#undef STAGE_B
#undef LDA
#undef LDB
#undef QUAD
#undef PHASE_SYNC

  // epilogue: C/D layout col=lane&15, row=(lane>>4)*4+reg  [m89-verified]
  const int colb = ln & 15, rowb = (ln >> 4) * 4;

  if constexpr (MODE == 0) {
    const int region = yb >> 2;                 // 4 y-blocks per 1024 cols
    const int nl0 = (yb & 3) * 256;
    const float* bias = region == 0 ? b0 : (region == 1 ? b1 : b2);
    ushort_t* gout    = region == 0 ? o0 : (region == 1 ? o1 : o2);
    const bool act = region < 2;
    ushort_t* Cs = (ushort_t*)smem;             // 256x256 bf16, chunk-XOR swizzled, 128 KB
    #pragma unroll
    for (int j = 0; j < 4; ++j) {
      const int col = wn * 64 + j * 16 + colb;
      const float bv_ = bias[nl0 + col];
      #pragma unroll
      for (int i = 0; i < 8; ++i) {
        const int rb_ = wm * 128 + i * 16 + rowb;
        #pragma unroll
        for (int r = 0; r < 4; ++r) {
          float v = acc[i][j][r] + bv_;
          if (act) v = (v > 0.f) ? v + 1.f : __expf(v);   // elu(v)+1
          const int row = rb_ + r;
          const int ch = col >> 3;
          Cs[row * 256 + ((ch ^ (row & 31)) << 3) + (col & 7)] = f2bf(v);
        }
      }
    }
    __syncthreads();
    #pragma unroll
    for (int c = 0; c < 16; ++c) {
      const int idx = c * 512 + tid;
      const int row = idx >> 5, ch = idx & 31;
      short8 t = *(const short8*)&Cs[row * 256 + ((ch ^ (row & 31)) << 3)];
      *(short8*)&gout[(size_t)(m0 + row) * D_MODEL + nl0 + ch * 8] = t;
    }
  } else {
    float* Cf = (float*)smem;                   // 128x256 fp32 per half, chunk-swizzled, 128 KB
    #pragma unroll
    for (int h = 0; h < 2; ++h) {
      if (h) __syncthreads();
      if (wm == h) {
        #pragma unroll
        for (int j = 0; j < 4; ++j) {
          const int col = wn * 64 + j * 16 + colb;
          const float bv_ = b0[n0 + col];
          #pragma unroll
          for (int i = 0; i < 8; ++i) {
            const int rl = i * 16 + rowb;
            #pragma unroll
            for (int r = 0; r < 4; ++r) {
              const int row = rl + r;
              const int ch = col >> 2;
              Cf[row * 256 + ((ch ^ (row & 7)) << 2) + (col & 3)] = acc[i][j][r] + bv_;
            }
          }
        }
      }
      __syncthreads();
      #pragma unroll
      for (int c = 0; c < 16; ++c) {
        const int idx = c * 512 + tid;
        const int row = idx >> 6, ch = idx & 63;
        float4 t = *(const float4*)&Cf[row * 256 + ((ch ^ (row & 7)) << 2)];
        *(float4*)&outf[(size_t)(m0 + h * 128 + row) * D_MODEL + n0 + ch * 4] = t;
      }
    }
  }
}

// ---------------- kv partial: per (b,h,chunk,wave) 64x64 outer-product sum + ksum ----------------
__global__ __launch_bounds__(256) void k_kv_partial(const ushort_t* __restrict__ kmat,
                                                    const ushort_t* __restrict__ vmat,
                                                    float* __restrict__ part) {
  __shared__ __align__(16) ushort_t sbuf[4][2][2][512];  // [wave][parity][k/v][8rows*64]
  const int tid = threadIdx.x, ln = tid & 63, w = tid >> 6;
  const int wb = __builtin_amdgcn_readfirstlane(w);
  const int bh = blockIdx.y, chunk = blockIdx.x;
  const int b = bh >> 4, h = bh & 15;
  const size_t cbase = ((size_t)b * SEQ + chunk * 1024 + w * 256) * D_MODEL + h * 64;
  const ushort_t* gk = kmat + cbase + (size_t)(ln >> 3) * D_MODEL + (ln & 7) * 8;
  const ushort_t* gv = vmat + cbase + (size_t)(ln >> 3) * D_MODEL + (ln & 7) * 8;

  float acc[8][8];
  float ksum[8];
  #pragma unroll
  for (int i = 0; i < 8; i++) { ksum[i] = 0.f;
    #pragma unroll
    for (int j = 0; j < 8; j++) acc[i][j] = 0.f; }

  const int r8 = (ln >> 3) * 8, c8 = (ln & 7) * 8;
  gll16(gk, &sbuf[wb][0][0][0]);
  gll16(gv, &sbuf[wb][0][1][0]);
  gk += 8 * D_MODEL; gv += 8 * D_MODEL;

  for (int bt = 0; bt < 32; bt++) {
    const int p = bt & 1;
    if (bt < 31) {
      gll16(gk, &sbuf[wb][p ^ 1][0][0]);
      gll16(gv, &sbuf[wb][p ^ 1][1][0]);
      gk += 8 * D_MODEL; gv += 8 * D_MODEL;
      __builtin_amdgcn_s_waitcnt(0x0F72);  // vmcnt(2): current batch landed
    } else {
      __builtin_amdgcn_s_waitcnt(0x0F70);  // vmcnt(0)
    }
    #pragma unroll
    for (int s = 0; s < 8; s++) {
      short8 kk = *(const short8*)&sbuf[wb][p][0][s * 64 + r8];
      short8 vv = *(const short8*)&sbuf[wb][p][1][s * 64 + c8];
      float ka[8], va[8];
      #pragma unroll
      for (int i = 0; i < 8; i++) {
        ka[i] = __builtin_bit_cast(float, (uint32_t)(ushort_t)kk[i] << 16);
        va[i] = __builtin_bit_cast(float, (uint32_t)(ushort_t)vv[i] << 16);
      }
      #pragma unroll
      for (int i = 0; i < 8; i++) {
        ksum[i] += ka[i];
        #pragma unroll
        for (int j = 0; j < 8; j++) acc[i][j] += ka[i] * va[j];
      }
    }
  }
  float* p0 = part + ((size_t)bh * 32 + chunk * 4 + w) * 4160;
  #pragma unroll
  for (int i = 0; i < 8; i++)
    #pragma unroll
    for (int j = 0; j < 8; j++) p0[(r8 + i) * 64 + c8 + j] = acc[i][j];
  if ((ln & 7) == 0) {
    #pragma unroll
    for (int i = 0; i < 8; i++) p0[4096 + r8 + i] = ksum[i];
  }
}

// ---------------- reduce partials -> kvT bf16 [bh][65][64] (row m holds kv[.][m]; row 64 = ksum) ----------------
__global__ void k_kv_reduce(const float* __restrict__ part, ushort_t* __restrict__ kvt) {
  const int bh = blockIdx.x, tid = threadIdx.x;
  const float* p0 = part + (size_t)bh * 32 * 4160;
  for (int idx = tid; idx < 4160; idx += 256) {
    float s = 0.f;
    #pragma unroll 4
    for (int c = 0; c < 32; c++) s += p0[(size_t)c * 4160 + idx];
    ushort_t bf = f2bf(s);
    if (idx < 4096) { int d = idx >> 6, m = idx & 63; kvt[(size_t)bh * 4160 + m * 64 + d] = bf; }
    else            { kvt[(size_t)bh * 4160 + 4096 + (idx - 4096)] = bf; }
  }
}

// ---------------- attn: out = (q @ kv) / max(q . ksum, eps), bf16 out ----------------
__global__ __launch_bounds__(256) void k_attn(const ushort_t* __restrict__ qmat,
                                              const ushort_t* __restrict__ kvt,
                                              ushort_t* __restrict__ attn) {
  __shared__ __align__(16) ushort_t kvs[65 * 80];     // kvT rows stride 80
  __shared__ __align__(16) ushort_t qs[4][64 * 80];   // per-wave q tile, stride 80
  const int tid = threadIdx.x, ln = tid & 63, w = tid >> 6;
  const int bh = blockIdx.y, b = bh >> 4, h = bh & 15;

  for (int idx = tid; idx < 4160; idx += 256) {
    int m = idx >> 6, d = idx & 63;
    kvs[m * 80 + d] = kvt[(size_t)bh * 4160 + idx];
  }
  const size_t s0 = (size_t)b * SEQ + blockIdx.x * 256 + w * 64;
  #pragma unroll
  for (int c = 0; c < 8; c++) {
    int f = c * 64 + ln;
    int row = f >> 3, dg = (f & 7) * 8;
    short8 t = *(const short8*)&qmat[(s0 + row) * D_MODEL + h * 64 + dg];
    *(short8*)&qs[w][row * 80 + dg] = t;
  }
  __syncthreads();

  const int ar = ln & 15, aq = (ln >> 4) * 8;
  f32x4 acc[4][4], nacc[4];
  #pragma unroll
  for (int i = 0; i < 4; i++) { nacc[i] = (f32x4){0.f, 0.f, 0.f, 0.f};
    #pragma unroll
    for (int j = 0; j < 4; j++) acc[i][j] = (f32x4){0.f, 0.f, 0.f, 0.f}; }

  #pragma unroll
  for (int kk = 0; kk < 2; kk++) {
    const int ko = kk * 32 + aq;
    bf16x8 a[4], bb[4], bn;
    #pragma unroll
    for (int i = 0; i < 4; i++) a[i] = *(const bf16x8*)&qs[w][(i * 16 + ar) * 80 + ko];
    #pragma unroll
    for (int j = 0; j < 4; j++) bb[j] = *(const bf16x8*)&kvs[(j * 16 + ar) * 80 + ko];
    bn = *(const bf16x8*)&kvs[64 * 80 + ko];
    #pragma unroll
    for (int i = 0; i < 4; i++) {
      #pragma unroll
      for (int j = 0; j < 4; j++)
        acc[i][j] = __builtin_amdgcn_mfma_f32_16x16x32_bf16(a[i], bb[j], acc[i][j], 0, 0, 0);
      nacc[i] = __builtin_amdgcn_mfma_f32_16x16x32_bf16(a[i], bn, nacc[i], 0, 0, 0);
    }
  }

  const int colb = ln & 15, rowb = (ln >> 4) * 4;
  #pragma unroll
  for (int i = 0; i < 4; i++) {
    #pragma unroll
    for (int r = 0; r < 4; r++) {
      const int row = i * 16 + rowb + r;
      float nm = fmaxf(nacc[i][r], 1e-6f);
      float inv = 1.0f / nm;
      const size_t grow = s0 + row;
      #pragma unroll
      for (int j = 0; j < 4; j++) {
        float v = acc[i][j][r] * inv;
        attn[grow * D_MODEL + h * 64 + j * 16 + colb] = f2bf(v);
      }
    }
  }
}

extern "C" void kernel_launch(void* const* d_in, const int* in_sizes, int n_in,
                              void* d_out, int out_size, void* d_ws, size_t ws_size,
                              hipStream_t stream) {
  const float* x  = (const float*)d_in[0];
  const float* Wq = (const float*)d_in[1];
  const float* bq = (const float*)d_in[2];
  const float* Wk = (const float*)d_in[3];
  const float* bk = (const float*)d_in[4];
  const float* Wv = (const float*)d_in[5];
  const float* bv = (const float*)d_in[6];
  const float* Wo = (const float*)d_in[7];
  const float* bo = (const float*)d_in[8];
  float* out = (float*)d_out;

  const int M = in_sizes[0] / D_MODEL;       // 32768
  const int B = M / SEQ;                     // 4
  const int BH = B * 16;                     // 64

  char* ws = (char*)d_ws;
  size_t off = 0;
  auto alloc = [&](size_t bytes) { char* p = ws + off; off += (bytes + 255) & ~(size_t)255; return p; };
  const size_t mb = (size_t)M * D_MODEL * 2;               // 64 MB per bf16 matrix
  ushort_t* xb    = (ushort_t*)alloc(mb);
  ushort_t* qb    = (ushort_t*)alloc(mb);
  ushort_t* kb    = (ushort_t*)alloc(mb);
  ushort_t* vb    = (ushort_t*)alloc(mb);
  ushort_t* attnb = (ushort_t*)alloc(mb);
  ushort_t* wqkvt = (ushort_t*)alloc((size_t)3 * D_MODEL * D_MODEL * 2);
  ushort_t* wot   = (ushort_t*)alloc((size_t)D_MODEL * D_MODEL * 2);
  ushort_t* kvt   = (ushort_t*)alloc((size_t)BH * 4160 * 2);
  float*    part  = (float*)   alloc((size_t)BH * 32 * 4160 * 4);
  (void)ws_size; (void)n_in; (void)out_size;

  const int n = M * D_MODEL;
  k_convert_x<<<n / (256 * 8), 256, 0, stream>>>(x, xb, n);
  k_transpose_w<<<dim3(16, 16, 4), 256, 0, stream>>>(Wq, Wk, Wv, Wo, wqkvt, wot);

  // Fused QKV: N = 3072, 256x256 tiles, 1D grid decoded N-fastest + XCD swizzle
  k_gemm<0, 12><<<(M / 256) * 12, 512, 0, stream>>>(xb, wqkvt, bq, bk, bv, qb, kb, vb, nullptr);

  k_kv_partial<<<dim3(8, BH), 256, 0, stream>>>(kb, vb, part);
  k_kv_reduce<<<BH, 256, 0, stream>>>(part, kvt);
  k_attn<<<dim3(SEQ / 256, BH), 256, 0, stream>>>(qb, kvt, attnb);

  // Output projection: fp32 out
  k_gemm<2, 4><<<(M / 256) * 4, 512, 0, stream>>>(attnb, wot, bo, nullptr, nullptr, nullptr, nullptr, nullptr, out);
}

// Round 2
// 668.477 us; speedup vs baseline: 1.1109x; 1.0077x over previous
//
#include <hip/hip_runtime.h>
#include <cstdint>
#include <cstddef>

#define D_MODEL 1024
#define SEQ 8192

typedef __bf16  bf16x8 __attribute__((ext_vector_type(8)));
typedef short   short8 __attribute__((ext_vector_type(8)));
typedef float   f32x4  __attribute__((ext_vector_type(4)));
typedef unsigned short ushort_t;

__device__ __forceinline__ ushort_t f2bf(float f) {
  uint32_t u = __builtin_bit_cast(uint32_t, f);
  u += 0x7FFFu + ((u >> 16) & 1u);          // round-to-nearest-even
  return (ushort_t)(u >> 16);
}
// async global->LDS, 16B per lane. LDS dest is wave-uniform base + lane*16.
__device__ __forceinline__ void gll16(const void* g, void* l) {
  __builtin_amdgcn_global_load_lds(
      (const __attribute__((address_space(1))) void*)g,
      (__attribute__((address_space(3))) void*)l, 16, 0, 0);
}
// stage one 128x64 bf16 half-tile (16 KB): 2 gll16 per lane, 8 waves cover 128 rows.
__device__ __forceinline__ void stage_half(const ushort_t* g, char* l0) {
  gll16(g, l0);                       // rows  0..63 of half
  gll16(g + 65536, l0 + 8192);        // rows 64..127 of half (+64*1024 elems)
}

// ---------------- fp32 -> bf16 conversion of x ----------------
__global__ void k_convert_x(const float* __restrict__ x, ushort_t* __restrict__ xb, int n) {
  int i = (blockIdx.x * 256 + threadIdx.x) * 8;
  if (i >= n) return;
  float4 v0 = *(const float4*)(x + i);
  float4 v1 = *(const float4*)(x + i + 4);
  ushort_t o[8] = { f2bf(v0.x), f2bf(v0.y), f2bf(v0.z), f2bf(v0.w),
                    f2bf(v1.x), f2bf(v1.y), f2bf(v1.z), f2bf(v1.w) };
  *(short8*)(xb + i) = *(const short8*)o;
}

// ---------------- W (k,n) fp32 -> Wt (n,k) bf16; z<3 -> fused qkv buffer ----------------
__global__ void k_transpose_w(const float* W0, const float* W1, const float* W2, const float* W3,
                              ushort_t* Tqkv, ushort_t* To) {
  const float* src; ushort_t* dst;
  switch (blockIdx.z) {
    case 0: src = W0; dst = Tqkv; break;
    case 1: src = W1; dst = Tqkv + (size_t)1024 * 1024; break;
    case 2: src = W2; dst = Tqkv + (size_t)2048 * 1024; break;
    default: src = W3; dst = To; break;
  }
  __shared__ float tile[64][65];
  int tx = threadIdx.x;
  int c = tx & 63, r0 = tx >> 6;
  int bx = blockIdx.x * 64, by = blockIdx.y * 64;
  #pragma unroll
  for (int i = 0; i < 16; i++) {
    int r = i * 4 + r0;
    tile[r][c] = src[(size_t)(by + r) * D_MODEL + bx + c];
  }
  __syncthreads();
  #pragma unroll
  for (int i = 0; i < 16; i++) {
    int r = i * 4 + r0;
    dst[(size_t)(bx + r) * D_MODEL + by + c] = f2bf(tile[c][r]);
  }
}

// ---------------- 256x256-tile read-ahead-pipelined bf16 GEMM ----------------
// C = A(M,K) * Bt(N,K)^T + bias.  BK=64, 8 waves (2Mx4N), LDS 128KB dbuf.
// Phase p covers 32 A-rows x all 64 B-cols per wave (16 MFMA). All frags are
// read ONE PHASE AHEAD with counted lgkmcnt (4/8/8/4), so LDS drain overlaps
// the previous phase's MFMA. Staging: 1 half-tile/phase; counted vmcnt(2) at
// ph0-end ((t+1).B landed) and ph2-end ((t+1).A landed); vmcnt(0) only at the
// t=14 tail. T1 bijective XCD swizzle, T2 chunk-XOR swizzle, T5 setprio.
// MODE 0: fused QKV (N=3072): region 0/1 -> elu+1 -> o0/o1; region 2 -> o2. bf16 out.
// MODE 2: fp32 out (+bias), single output.
template<int MODE, int NY>
__global__ __launch_bounds__(512, 2) void k_gemm(const ushort_t* __restrict__ A,
                                                 const ushort_t* __restrict__ Bt,
                                                 const float* __restrict__ b0,
                                                 const float* __restrict__ b1,
                                                 const float* __restrict__ b2,
                                                 ushort_t* __restrict__ o0,
                                                 ushort_t* __restrict__ o1,
                                                 ushort_t* __restrict__ o2,
                                                 float* __restrict__ outf) {
  __shared__ __align__(16) char smem[131072];   // 2 x (A 32KB + B 32KB) dbuf; epilogue reuses

  const int nwg = gridDim.x;
  const int bid0 = blockIdx.x;
  const int bid = (bid0 & 7) * (nwg >> 3) + (bid0 >> 3);   // XCD-aware, bijective (nwg%8==0)
  const int xb = bid / NY, yb = bid % NY;                  // N-fastest: A-panel L2 reuse
  const int m0 = xb * 256, n0 = yb * 256;

  const int tid = threadIdx.x;
  const int ln = tid & 63;
  const int w  = tid >> 6;
  const int wb = __builtin_amdgcn_readfirstlane(w);
  const int wm = wb >> 2, wn = wb & 3;          // 2x4 wave grid; per-wave C = 128x64

  // --- staging: thread's (row,chunk) slot; global chunk pre-swizzled (c ^= row&7) ---
  const int srow = wb * 8 + (ln >> 3);                       // row in half-tile
  const int schk = ((ln & 7) ^ ((ln >> 3) & 7)) * 8;         // swizzled source chunk (elems)
  const ushort_t* gA = A  + (size_t)(m0 + srow) * D_MODEL + schk;
  const ushort_t* gB = Bt + (size_t)(n0 + srow) * D_MODEL + schk;

#define STG_A(BASE, H, T) stage_half(gA + (size_t)(T) * 64 + (size_t)(H) * 131072, smem + (BASE) + (H) * 16384 + wb * 1024)
#define STG_B(BASE, H, T) stage_half(gB + (size_t)(T) * 64 + (size_t)(H) * 131072, smem + (BASE) + 32768 + (H) * 16384 + wb * 1024)

#define VMW_(N) asm volatile("s_waitcnt vmcnt(" #N ")" ::: "memory")
#define VMW(N)  VMW_(N)
#define LGW_(N) asm volatile("s_waitcnt lgkmcnt(" #N ")" ::: "memory")
#define LGW(N)  do { LGW_(N); __builtin_amdgcn_sched_barrier(0); } while (0)

  f32x4 acc[8][4];
  #pragma unroll
  for (int i = 0; i < 8; i++)
    #pragma unroll
    for (int j = 0; j < 4; j++) acc[i][j] = (f32x4){0.f, 0.f, 0.f, 0.f};
  bf16x8 aX[2][2], aY[2][2];        // A chunk frags (32 rows x 64 K), phase-alternating
  bf16x8 bX[4][2], bY[4][2];        // full B tile frags (64 cols x 64 K), tile-alternating

  const int ar  = ln & 15;
  const int cw0 = (((ln >> 4)    ) ^ (ln & 7)) << 4;         // swizzled 16B chunk offs, ksub0
  const int cw1 = (((ln >> 4) + 4) ^ (ln & 7)) << 4;         // ksub1
  const int arow = wm * 128 + ar;
  const int brow = wn * 64 + ar;

#define LDA2(DST, BASE, CH) { _Pragma("unroll") for (int m_ = 0; m_ < 2; ++m_) { \
    const char* p_ = smem + (BASE) + ((arow + (CH) * 32 + m_ * 16) << 7); \
    DST[m_][0] = *(const bf16x8*)(p_ + cw0); DST[m_][1] = *(const bf16x8*)(p_ + cw1); } }
#define LDB2(DST, BASE, J0) { _Pragma("unroll") for (int j_ = 0; j_ < 2; ++j_) { \
    const char* p_ = smem + (BASE) + 32768 + ((brow + ((J0) + j_) * 16) << 7); \
    DST[(J0) + j_][0] = *(const bf16x8*)(p_ + cw0); DST[(J0) + j_][1] = *(const bf16x8*)(p_ + cw1); } }
#define MF8(P, ASET, BSET) { _Pragma("unroll") for (int m_ = 0; m_ < 2; ++m_) \
    _Pragma("unroll") for (int j_ = 0; j_ < 4; ++j_) { \
      acc[(P)*2+m_][j_] = __builtin_amdgcn_mfma_f32_16x16x32_bf16(ASET[m_][0], BSET[j_][0], acc[(P)*2+m_][j_], 0, 0, 0); \
      acc[(P)*2+m_][j_] = __builtin_amdgcn_mfma_f32_16x16x32_bf16(ASET[m_][1], BSET[j_][1], acc[(P)*2+m_][j_], 0, 0, 0); } }

#define ENDBAR { __builtin_amdgcn_s_barrier(); __builtin_amdgcn_sched_barrier(0); }

  // One K-tile, 4 read-ahead phases. CUR/NXT: LDS byte bases (compile-time).
  // BC: B frags of tile T (consumed); BN: B frags of tile T+1 (filled ph1/ph2).
  // H1: tile T+1 exists; H2: tile T+2 exists. L1..L3: counted lgkm for ph1..ph3.
  // V2: vmcnt count at ph2-end (2 steady, 0 at the T=14 tail drain).
#define TILE(T, CUR, NXT, BC, BN, H1, H2, L1, L2, L3, V2) { \
    /* ph0: consume A-c0; read A-c1; stage (T+1).A0 */ \
    LDA2(aY, CUR, 1); \
    if (H1) STG_A(NXT, 0, (T) + 1); \
    __builtin_amdgcn_s_barrier(); \
    LGW(4); \
    __builtin_amdgcn_s_setprio(1); MF8(0, aX, BC); __builtin_amdgcn_s_setprio(0); \
    VMW(2); \
    ENDBAR; \
    /* ph1: consume A-c1; read A-c2 + B'(nj0,1); stage (T+1).A1 */ \
    LDA2(aX, CUR, 2); \
    if (H1) LDB2(BN, NXT, 0); \
    if (H1) STG_A(NXT, 1, (T) + 1); \
    __builtin_amdgcn_s_barrier(); \
    LGW(L1); \
    __builtin_amdgcn_s_setprio(1); MF8(1, aY, BC); __builtin_amdgcn_s_setprio(0); \
    ENDBAR; \
    /* ph2: consume A-c2; read A-c3 + B'(nj2,3); stage (T+2).B0 */ \
    LDA2(aY, CUR, 3); \
    if (H1) LDB2(BN, NXT, 2); \
    if (H2) STG_B(CUR, 0, (T) + 2); \
    __builtin_amdgcn_s_barrier(); \
    LGW(L2); \
    __builtin_amdgcn_s_setprio(1); MF8(2, aX, BC); __builtin_amdgcn_s_setprio(0); \
    VMW(V2); \
    ENDBAR; \
    /* ph3: consume A-c3; read A(T+1)-c0; stage (T+2).B1 */ \
    if (H1) LDA2(aX, NXT, 0); \
    if (H2) STG_B(CUR, 1, (T) + 2); \
    __builtin_amdgcn_s_barrier(); \
    LGW(L3); \
    __builtin_amdgcn_s_setprio(1); MF8(3, aY, BC); __builtin_amdgcn_s_setprio(0); \
    ENDBAR; \
  }

  // prologue: tile0 all 4 halves + tile1 B halves; vmcnt(4) -> tile0 landed,
  // tile1.B's 4 loads stay in flight (steady-state invariant entering t=0).
  STG_A(0, 0, 0); STG_A(0, 1, 0); STG_B(0, 0, 0); STG_B(0, 1, 0);
  STG_B(65536, 0, 1); STG_B(65536, 1, 1);
  VMW(4);
  __builtin_amdgcn_s_barrier();
  __builtin_amdgcn_sched_barrier(0);
  LDA2(aX, 0, 0);                 // A(0, chunk0)
  LDB2(bX, 0, 0); LDB2(bX, 0, 2); // B(0) all nj

  #pragma unroll 1
  for (int kt = 0; kt < 14; kt += 2) {
    TILE(kt,     0,     65536, bX, bY, true, true, 8, 8, 4, 2);
    TILE(kt + 1, 65536, 0,     bY, bX, true, true, 8, 8, 4, 2);
  }
  TILE(14, 0,     65536, bX, bY, true,  false, 8, 8, 4, 0);  // drain: vmcnt(0) at ph2-end
  TILE(15, 65536, 0,     bY, bX, false, false, 4, 4, 0, 2);

#undef STG_A
#undef STG_B
#undef LDA2
#undef LDB2
#undef MF8
#undef TILE
#undef ENDBAR

  // epilogue: C/D layout col=lane&15, row=(lane>>4)*4+reg  [m89-verified]
  // acc[i][j]: rows i*16 (i=0..7), cols j*16 (j=0..3) within wave's 128x64.
  const int colb = ln & 15, rowb = (ln >> 4) * 4;

  if constexpr (MODE == 0) {
    const int region = yb >> 2;                 // 4 y-blocks per 1024 cols
    const int nl0 = (yb & 3) * 256;
    const float* bias = region == 0 ? b0 : (region == 1 ? b1 : b2);
    ushort_t* gout    = region == 0 ? o0 : (region == 1 ? o1 : o2);
    const bool act = region < 2;
    ushort_t* Cs = (ushort_t*)smem;             // 256x256 bf16, chunk-XOR swizzled, 128 KB
    #pragma unroll
    for (int j = 0; j < 4; ++j) {
      const int col = wn * 64 + j * 16 + colb;
      const float bv_ = bias[nl0 + col];
      #pragma unroll
      for (int i = 0; i < 8; ++i) {
        const int rb_ = wm * 128 + i * 16 + rowb;
        #pragma unroll
        for (int r = 0; r < 4; ++r) {
          float v = acc[i][j][r] + bv_;
          if (act) v = (v > 0.f) ? v + 1.f : __expf(v);   // elu(v)+1
          const int row = rb_ + r;
          const int ch = col >> 3;
          Cs[row * 256 + ((ch ^ (row & 31)) << 3) + (col & 7)] = f2bf(v);
        }
      }
    }
    __syncthreads();
    #pragma unroll
    for (int c = 0; c < 16; ++c) {
      const int idx = c * 512 + tid;
      const int row = idx >> 5, ch = idx & 31;
      short8 t = *(const short8*)&Cs[row * 256 + ((ch ^ (row & 31)) << 3)];
      *(short8*)&gout[(size_t)(m0 + row) * D_MODEL + nl0 + ch * 8] = t;
    }
  } else {
    float* Cf = (float*)smem;                   // 128x256 fp32 per half, chunk-swizzled, 128 KB
    #pragma unroll
    for (int h = 0; h < 2; ++h) {
      if (h) __syncthreads();
      if (wm == h) {
        #pragma unroll
        for (int j = 0; j < 4; ++j) {
          const int col = wn * 64 + j * 16 + colb;
          const float bv_ = b0[n0 + col];
          #pragma unroll
          for (int i = 0; i < 8; ++i) {
            const int rl = i * 16 + rowb;
            #pragma unroll
            for (int r = 0; r < 4; ++r) {
              const int row = rl + r;
              const int ch = col >> 2;
              Cf[row * 256 + ((ch ^ (row & 7)) << 2) + (col & 3)] = acc[i][j][r] + bv_;
            }
          }
        }
      }
      __syncthreads();
      #pragma unroll
      for (int c = 0; c < 16; ++c) {
        const int idx = c * 512 + tid;
        const int row = idx >> 6, ch = idx & 63;
        float4 t = *(const float4*)&Cf[row * 256 + ((ch ^ (row & 7)) << 2)];
        *(float4*)&outf[(size_t)(m0 + h * 128 + row) * D_MODEL + n0 + ch * 4] = t;
      }
    }
  }
#undef VMW_
#undef VMW
#undef LGW_
#undef LGW
}

// ---------------- kv partial: per (b,h,chunk,wave) 64x64 outer-product sum + ksum ----------------
__global__ __launch_bounds__(256) void k_kv_partial(const ushort_t* __restrict__ kmat,
                                                    const ushort_t* __restrict__ vmat,
                                                    float* __restrict__ part) {
  __shared__ __align__(16) ushort_t sbuf[4][2][2][512];  // [wave][parity][k/v][8rows*64]
  const int tid = threadIdx.x, ln = tid & 63, w = tid >> 6;
  const int wb = __builtin_amdgcn_readfirstlane(w);
  const int bh = blockIdx.y, chunk = blockIdx.x;
  const int b = bh >> 4, h = bh & 15;
  const size_t cbase = ((size_t)b * SEQ + chunk * 1024 + w * 256) * D_MODEL + h * 64;
  const ushort_t* gk = kmat + cbase + (size_t)(ln >> 3) * D_MODEL + (ln & 7) * 8;
  const ushort_t* gv = vmat + cbase + (size_t)(ln >> 3) * D_MODEL + (ln & 7) * 8;

  float acc[8][8];
  float ksum[8];
  #pragma unroll
  for (int i = 0; i < 8; i++) { ksum[i] = 0.f;
    #pragma unroll
    for (int j = 0; j < 8; j++) acc[i][j] = 0.f; }

  const int r8 = (ln >> 3) * 8, c8 = (ln & 7) * 8;
  gll16(gk, &sbuf[wb][0][0][0]);
  gll16(gv, &sbuf[wb][0][1][0]);
  gk += 8 * D_MODEL; gv += 8 * D_MODEL;

  for (int bt = 0; bt < 32; bt++) {
    const int p = bt & 1;
    if (bt < 31) {
      gll16(gk, &sbuf[wb][p ^ 1][0][0]);
      gll16(gv, &sbuf[wb][p ^ 1][1][0]);
      gk += 8 * D_MODEL; gv += 8 * D_MODEL;
      __builtin_amdgcn_s_waitcnt(0x0F72);  // vmcnt(2): current batch landed
    } else {
      __builtin_amdgcn_s_waitcnt(0x0F70);  // vmcnt(0)
    }
    #pragma unroll
    for (int s = 0; s < 8; s++) {
      short8 kk = *(const short8*)&sbuf[wb][p][0][s * 64 + r8];
      short8 vv = *(const short8*)&sbuf[wb][p][1][s * 64 + c8];
      float ka[8], va[8];
      #pragma unroll
      for (int i = 0; i < 8; i++) {
        ka[i] = __builtin_bit_cast(float, (uint32_t)(ushort_t)kk[i] << 16);
        va[i] = __builtin_bit_cast(float, (uint32_t)(ushort_t)vv[i] << 16);
      }
      #pragma unroll
      for (int i = 0; i < 8; i++) {
        ksum[i] += ka[i];
        #pragma unroll
        for (int j = 0; j < 8; j++) acc[i][j] += ka[i] * va[j];
      }
    }
  }
  float* p0 = part + ((size_t)bh * 32 + chunk * 4 + w) * 4160;
  #pragma unroll
  for (int i = 0; i < 8; i++)
    #pragma unroll
    for (int j = 0; j < 8; j++) p0[(r8 + i) * 64 + c8 + j] = acc[i][j];
  if ((ln & 7) == 0) {
    #pragma unroll
    for (int i = 0; i < 8; i++) p0[4096 + r8 + i] = ksum[i];
  }
}

// ---------------- reduce partials -> kvT bf16 [bh][65][64] (row m holds kv[.][m]; row 64 = ksum) ----------------
__global__ void k_kv_reduce(const float* __restrict__ part, ushort_t* __restrict__ kvt) {
  const int bh = blockIdx.x, tid = threadIdx.x;
  const float* p0 = part + (size_t)bh * 32 * 4160;
  for (int idx = tid; idx < 4160; idx += 256) {
    float s = 0.f;
    #pragma unroll 4
    for (int c = 0; c < 32; c++) s += p0[(size_t)c * 4160 + idx];
    ushort_t bf = f2bf(s);
    if (idx < 4096) { int d = idx >> 6, m = idx & 63; kvt[(size_t)bh * 4160 + m * 64 + d] = bf; }
    else            { kvt[(size_t)bh * 4160 + 4096 + (idx - 4096)] = bf; }
  }
}

// ---------------- attn: out = (q @ kv) / max(q . ksum, eps), bf16 out ----------------
__global__ __launch_bounds__(256) void k_attn(const ushort_t* __restrict__ qmat,
                                              const ushort_t* __restrict__ kvt,
                                              ushort_t* __restrict__ attn) {
  __shared__ __align__(16) ushort_t kvs[65 * 80];     // kvT rows stride 80
  __shared__ __align__(16) ushort_t qs[4][64 * 80];   // per-wave q tile, stride 80
  const int tid = threadIdx.x, ln = tid & 63, w = tid >> 6;
  const int bh = blockIdx.y, b = bh >> 4, h = bh & 15;

  for (int idx = tid; idx < 4160; idx += 256) {
    int m = idx >> 6, d = idx & 63;
    kvs[m * 80 + d] = kvt[(size_t)bh * 4160 + idx];
  }
  const size_t s0 = (size_t)b * SEQ + blockIdx.x * 256 + w * 64;
  #pragma unroll
  for (int c = 0; c < 8; c++) {
    int f = c * 64 + ln;
    int row = f >> 3, dg = (f & 7) * 8;
    short8 t = *(const short8*)&qmat[(s0 + row) * D_MODEL + h * 64 + dg];
    *(short8*)&qs[w][row * 80 + dg] = t;
  }
  __syncthreads();

  const int ar = ln & 15, aq = (ln >> 4) * 8;
  f32x4 acc[4][4], nacc[4];
  #pragma unroll
  for (int i = 0; i < 4; i++) { nacc[i] = (f32x4){0.f, 0.f, 0.f, 0.f};
    #pragma unroll
    for (int j = 0; j < 4; j++) acc[i][j] = (f32x4){0.f, 0.f, 0.f, 0.f}; }

  #pragma unroll
  for (int kk = 0; kk < 2; kk++) {
    const int ko = kk * 32 + aq;
    bf16x8 a[4], bb[4], bn;
    #pragma unroll
    for (int i = 0; i < 4; i++) a[i] = *(const bf16x8*)&qs[w][(i * 16 + ar) * 80 + ko];
    #pragma unroll
    for (int j = 0; j < 4; j++) bb[j] = *(const bf16x8*)&kvs[(j * 16 + ar) * 80 + ko];
    bn = *(const bf16x8*)&kvs[64 * 80 + ko];
    #pragma unroll
    for (int i = 0; i < 4; i++) {
      #pragma unroll
      for (int j = 0; j < 4; j++)
        acc[i][j] = __builtin_amdgcn_mfma_f32_16x16x32_bf16(a[i], bb[j], acc[i][j], 0, 0, 0);
      nacc[i] = __builtin_amdgcn_mfma_f32_16x16x32_bf16(a[i], bn, nacc[i], 0, 0, 0);
    }
  }

  const int colb = ln & 15, rowb = (ln >> 4) * 4;
  #pragma unroll
  for (int i = 0; i < 4; i++) {
    #pragma unroll
    for (int r = 0; r < 4; r++) {
      const int row = i * 16 + rowb + r;
      float nm = fmaxf(nacc[i][r], 1e-6f);
      float inv = 1.0f / nm;
      const size_t grow = s0 + row;
      #pragma unroll
      for (int j = 0; j < 4; j++) {
        float v = acc[i][j][r] * inv;
        attn[grow * D_MODEL + h * 64 + j * 16 + colb] = f2bf(v);
      }
    }
  }
}

extern "C" void kernel_launch(void* const* d_in, const int* in_sizes, int n_in,
                              void* d_out, int out_size, void* d_ws, size_t ws_size,
                              hipStream_t stream) {
  const float* x  = (const float*)d_in[0];
  const float* Wq = (const float*)d_in[1];
  const float* bq = (const float*)d_in[2];
  const float* Wk = (const float*)d_in[3];
  const float* bk = (const float*)d_in[4];
  const float* Wv = (const float*)d_in[5];
  const float* bv = (const float*)d_in[6];
  const float* Wo = (const float*)d_in[7];
  const float* bo = (const float*)d_in[8];
  float* out = (float*)d_out;

  const int M = in_sizes[0] / D_MODEL;       // 32768
  const int B = M / SEQ;                     // 4
  const int BH = B * 16;                     // 64

  char* ws = (char*)d_ws;
  size_t off = 0;
  auto alloc = [&](size_t bytes) { char* p = ws + off; off += (bytes + 255) & ~(size_t)255; return p; };
  const size_t mb = (size_t)M * D_MODEL * 2;               // 64 MB per bf16 matrix
  ushort_t* xb    = (ushort_t*)alloc(mb);
  ushort_t* qb    = (ushort_t*)alloc(mb);
  ushort_t* kb    = (ushort_t*)alloc(mb);
  ushort_t* vb    = (ushort_t*)alloc(mb);
  ushort_t* attnb = (ushort_t*)alloc(mb);
  ushort_t* wqkvt = (ushort_t*)alloc((size_t)3 * D_MODEL * D_MODEL * 2);
  ushort_t* wot   = (ushort_t*)alloc((size_t)D_MODEL * D_MODEL * 2);
  ushort_t* kvt   = (ushort_t*)alloc((size_t)BH * 4160 * 2);
  float*    part  = (float*)   alloc((size_t)BH * 32 * 4160 * 4);
  (void)ws_size; (void)n_in; (void)out_size;

  const int n = M * D_MODEL;
  k_convert_x<<<n / (256 * 8), 256, 0, stream>>>(x, xb, n);
  k_transpose_w<<<dim3(16, 16, 4), 256, 0, stream>>>(Wq, Wk, Wv, Wo, wqkvt, wot);

  // Fused QKV: N = 3072, 256x256 tiles, 1D grid decoded N-fastest + XCD swizzle
  k_gemm<0, 12><<<(M / 256) * 12, 512, 0, stream>>>(xb, wqkvt, bq, bk, bv, qb, kb, vb, nullptr);

  k_kv_partial<<<dim3(8, BH), 256, 0, stream>>>(kb, vb, part);
  k_kv_reduce<<<BH, 256, 0, stream>>>(part, kvt);
  k_attn<<<dim3(SEQ / 256, BH), 256, 0, stream>>>(qb, kvt, attnb);

  // Output projection: fp32 out
  k_gemm<2, 4><<<(M / 256) * 4, 512, 0, stream>>>(attnb, wot, bo, nullptr, nullptr, nullptr, nullptr, nullptr, out);
}